// Round 2
// baseline (166.672 us; speedup 1.0000x reference)
//
#include <hip/hip_runtime.h>
#include <stdint.h>

#define DIM 1024
#define GLOBAL_AS __attribute__((address_space(1)))
#define LDS_AS __attribute__((address_space(3)))

typedef short bf16x8 __attribute__((ext_vector_type(8)));
typedef float f32x4 __attribute__((ext_vector_type(4)));

// deg-4 Taylor via depth-2: R = I + A + A2/2 + (C3*A + C4*A2)*A2
#define C3f 0.16666667f
#define C4f 0.041666668f

__device__ __forceinline__ unsigned short f32_to_bf16(float f) {
    union { float f; uint32_t u; } v; v.f = f;
    uint32_t u = v.u;
    u += 0x7FFFu + ((u >> 16) & 1u);   // round-to-nearest-even
    return (unsigned short)(u >> 16);
}
__device__ __forceinline__ float bf16_to_f32(unsigned short u) {
    union { uint32_t u; float f; } v; v.u = ((uint32_t)u) << 16;
    return v.f;
}

// async global->LDS, 16B per lane; LDS dst = wave-uniform base + lane*16.
__device__ __forceinline__ void async16(const void* g, void* l) {
    __builtin_amdgcn_global_load_lds((GLOBAL_AS const void*)g,
                                     (LDS_AS void*)l, 16, 0, 0);
}

// Coalesced A = W - W^T via 32x32 LDS tile transpose.
// Ab = bf16(A) (A-operand), G = bf16(-A) = bf16(A^T) (B-operand).
__global__ __launch_bounds__(256) void k_init(const float* __restrict__ W,
        unsigned short* __restrict__ Ab, unsigned short* __restrict__ G) {
    __shared__ float t2[32][33];
    int i0 = (blockIdx.x & 31) * 32, j0 = (blockIdx.x >> 5) * 32;
    int tx = threadIdx.x & 31, ty = threadIdx.x >> 5;
    float t1[4];
    #pragma unroll
    for (int p = 0; p < 4; p++) {
        int r = p * 8 + ty;
        t1[p] = W[(i0 + r) * DIM + j0 + tx];            // coalesced
        t2[r][tx] = W[(j0 + r) * DIM + i0 + tx];        // coalesced
    }
    __syncthreads();
    #pragma unroll
    for (int p = 0; p < 4; p++) {
        int r = p * 8 + ty;
        float a = t1[p] - t2[tx][r];                    // W[i][j] - W[j][i]
        int gi = (i0 + r) * DIM + j0 + tx;
        Ab[gi] = f32_to_bf16(a);
        G[gi]  = f32_to_bf16(-a);
    }
}

// 64x64-tile 1024^3 GEMM body (BK=256, 4 rounds, XOR swizzle, async staging).
// MODE 1 (k_g1): out1 = bf16(acc) = A2; out2 = bf16(C3*A + C4*acc) = P
// MODE 2 (k_g2): v = acc + I + A + A2/2; LDS-transpose; out1 = bf16(v^T) = R^T
// Fused: blocks [0,256) do GEMM; blocks [256, 256+4096) convert X half.
template<int MODE>
__device__ __forceinline__ void gemm_chain_body(
        const unsigned short* __restrict__ P,
        const unsigned short* __restrict__ Qt,
        const unsigned short* __restrict__ Ab,
        const unsigned short* __restrict__ A2b,
        unsigned short* __restrict__ out1,
        unsigned short* __restrict__ out2,
        const float* __restrict__ X,
        unsigned short* __restrict__ Xb,
        size_t xoff) {
    int bid = blockIdx.x;
    int tid = threadIdx.x;
    if (bid >= 256) {                        // ---- convert path (4096 blocks) ----
        size_t id = (size_t)(bid - 256) * 256 + tid;
        const f32x4* p = (const f32x4*)(X + xoff + id * 8);
        f32x4 v0 = p[0], v1 = p[1];
        unsigned short o[8];
        #pragma unroll
        for (int q = 0; q < 4; q++) { o[q] = f32_to_bf16(v0[q]); o[4 + q] = f32_to_bf16(v1[q]); }
        *(bf16x8*)&Xb[xoff + id * 8] = *(bf16x8*)o;
        return;
    }
    __shared__ unsigned short lA[64 * 256];   // 32 KB
    __shared__ unsigned short lB[64 * 256];   // 32 KB
    int m0 = (bid & 15) * 64, n0 = (bid >> 4) * 64;
    int lane = tid & 63, w = tid >> 6;
    int wr = w >> 1, wc = w & 1;
    int rr = lane & 15, ko = lane >> 4;
    f32x4 acc[2][2] = {};
    for (int ks = 0; ks < 4; ks++) {
        int kb = ks * 256;
        #pragma unroll
        for (int i = 0; i < 8; i++) {
            int l = i * 256 + tid;            // 0..2047 = 64 rows x 32 chunks
            int r = l >> 5, cst = l & 31;
            int cd = cst ^ (r & 7);
            async16(&P[(m0 + r) * DIM + kb + cd * 8], &lA[l * 8]);
            async16(&Qt[(n0 + r) * DIM + kb + cd * 8], &lB[l * 8]);
        }
        __syncthreads();
        #pragma unroll
        for (int s = 0; s < 8; s++) {
            int cd = s * 4 + ko;
            bf16x8 af[2], bq[2];
            #pragma unroll
            for (int mi = 0; mi < 2; mi++) {
                int ra = wr * 32 + mi * 16 + rr;
                af[mi] = *(const bf16x8*)&lA[ra * 256 + ((cd ^ (ra & 7)) * 8)];
            }
            #pragma unroll
            for (int ni = 0; ni < 2; ni++) {
                int rb = wc * 32 + ni * 16 + rr;
                bq[ni] = *(const bf16x8*)&lB[rb * 256 + ((cd ^ (rb & 7)) * 8)];
            }
            #pragma unroll
            for (int mi = 0; mi < 2; mi++)
                #pragma unroll
                for (int ni = 0; ni < 2; ni++)
                    acc[mi][ni] = __builtin_amdgcn_mfma_f32_16x16x32_bf16(
                        af[mi], bq[ni], acc[mi][ni], 0, 0, 0);
        }
        __syncthreads();
    }
    if (MODE == 1) {
        #pragma unroll
        for (int mi = 0; mi < 2; mi++)
            #pragma unroll
            for (int ni = 0; ni < 2; ni++)
                #pragma unroll
                for (int q = 0; q < 4; q++) {
                    int rl = wr * 32 + mi * 16 + ko * 4 + q;
                    int cl = wc * 32 + ni * 16 + rr;
                    int gi = (m0 + rl) * DIM + n0 + cl;
                    float v = acc[mi][ni][q];
                    out1[gi] = f32_to_bf16(v);
                    float a = bf16_to_f32(Ab[gi]);
                    out2[gi] = f32_to_bf16(C3f * a + C4f * v);
                }
    } else {
        float* tb = (float*)lA;               // 64*65*4 = 16.6 KB
        #pragma unroll
        for (int mi = 0; mi < 2; mi++)
            #pragma unroll
            for (int ni = 0; ni < 2; ni++)
                #pragma unroll
                for (int q = 0; q < 4; q++) {
                    int rl = wr * 32 + mi * 16 + ko * 4 + q;
                    int cl = wc * 32 + ni * 16 + rr;
                    int gi = (m0 + rl) * DIM + n0 + cl;
                    float a = bf16_to_f32(Ab[gi]);
                    float a2 = bf16_to_f32(A2b[gi]);
                    float d = (m0 + rl == n0 + cl) ? 1.0f : 0.0f;
                    tb[cl * 65 + rl] = acc[mi][ni][q] + d + a + 0.5f * a2;
                }
        __syncthreads();
        #pragma unroll
        for (int q = 0; q < 16; q++) {
            int l = tid * 16 + q;
            int orow = l >> 6, ocol = l & 63;
            out1[(n0 + orow) * DIM + m0 + ocol] = f32_to_bf16(tb[orow * 65 + ocol]);
        }
    }
}

__global__ __launch_bounds__(256) void k_g1(
        const unsigned short* __restrict__ Ab, const unsigned short* __restrict__ G,
        unsigned short* __restrict__ A2b, unsigned short* __restrict__ Pb,
        const float* __restrict__ X, unsigned short* __restrict__ Xb) {
    gemm_chain_body<1>(Ab, G, Ab, nullptr, A2b, Pb, X, Xb, 0);
}

__global__ __launch_bounds__(256) void k_g2(
        const unsigned short* __restrict__ Pb, const unsigned short* __restrict__ A2b,
        const unsigned short* __restrict__ Ab, unsigned short* __restrict__ Rtb,
        const float* __restrict__ X, unsigned short* __restrict__ Xb) {
    // A2^T = A2 (symmetric), so Qt = A2b row-major directly.
    gemm_chain_body<2>(Pb, A2b, Ab, A2b, Rtb, nullptr, X, Xb, (size_t)8388608);
}

// Out(16384x1024) = Xb(bf16) @ R, with Rtb = R^T row-major bf16.
// 256x256 tile, BK=64, 512 threads (8 waves as 2M x 4N), 128 KiB LDS dbuf,
// 8-phase schedule (m201 template): per phase {ds_read frag subtile; issue one
// 128-row half-tile stage (2 x global_load_lds); s_barrier; lgkmcnt(0);
// setprio(1); 16 MFMA (one C-quadrant, K=64); setprio(0); s_barrier}.
// Counted vmcnt(4) ONLY at phases 4/8, placed BEFORE the final barrier so the
// barrier publishes load completion to all waves. 2 half-tiles (4 loads) stay
// in flight across every barrier. Raw s_barrier (never __syncthreads) so the
// compiler cannot insert vmcnt(0) drains.
//
// Schedule (iteration i computes K-tiles t0=2i in buf0: P1-P4, t1=2i+1 in
// buf1: P5-P8; quadrant order (qm,qn) = (0,0),(0,1),(1,0),(1,1)):
//   P1: ld A0,B0(buf0)  stage B1(t1)->b1   P5: ld A0,B0(buf1)  stage B1(t2)->b0
//   P2: ld B1(buf0)     stage A1(t1)->b1   P6: ld B1(buf1)     stage A1(t2)->b0
//   P3: ld A1(buf0)     stage A0(t2)->b0   P7: ld A1(buf1)     stage A0(t3)->b1
//   P4: (regs)          stage B0(t2)->b0   P8: (regs)          stage B0(t3)->b1
// Every region is overwritten >=1 phase after its last ds_read (the reader's
// lgkmcnt(0) precedes that phase's final barrier -> safe).
// Interleaved frag mapping row = mi*32 + wr*16 + rr makes quadrant qm touch
// exactly A-half qm (rows qm*128..), and qn touch B-half qn, so each phase's
// deadline is one staged half-tile. ra&7 == rr&7 (mi*32, wr*16 = 0 mod 8), so
// the ds_read swizzle XOR is a per-thread constant.
__global__ __launch_bounds__(512, 2) void k_biggemm(
        const unsigned short* __restrict__ Xb,
        const unsigned short* __restrict__ Rtb,
        float* __restrict__ Out) {
    __shared__ unsigned short lA[2][256 * 64];   // 64 KB
    __shared__ unsigned short lB[2][256 * 64];   // 64 KB
    int tid = threadIdx.x;
    int bid = blockIdx.x;
    // XCD swizzle (nwg=256, 256%8==0 -> bijective): XCD x gets 8 m-panels with
    // all 4 n-tiles -> the 4 blocks sharing an Xb m-panel sit on one XCD's L2.
    int s = (bid & 7) * 32 + (bid >> 3);
    int m0 = (s >> 2) * 256, n0 = (s & 3) * 256;
    int lane = tid & 63, w = tid >> 6;
    int wr = w >> 2, wc = w & 3;                 // 2 x 4 wave grid
    int rr = lane & 15, ko = (lane >> 4) & 3;

    f32x4 acc[8][4] = {};                        // 128 x 64 per wave
    bf16x8 aF[4][2], bF[2][2][2];

    // Stage one half (128 rows) of the A/B K-tile kt into buf: 2 loads/thread.
    // LDS dest linear; source chunk pre-swizzled (c ^ (r&7)) so swizzled
    // ds_read finds data in place (involution).
    auto stageA = [&](int buf, int kt, int h) {
        #pragma unroll
        for (int l = 0; l < 2; l++) {
            int L = h * 1024 + l * 512 + tid;
            int r = L >> 3, c = L & 7;
            async16(&Xb[(size_t)(m0 + r) * DIM + kt * 64 + ((c ^ (r & 7)) * 8)],
                    &lA[buf][L * 8]);
        }
    };
    auto stageB = [&](int buf, int kt, int h) {
        #pragma unroll
        for (int l = 0; l < 2; l++) {
            int L = h * 1024 + l * 512 + tid;
            int r = L >> 3, c = L & 7;
            async16(&Rtb[(size_t)(n0 + r) * DIM + kt * 64 + ((c ^ (r & 7)) * 8)],
                    &lB[buf][L * 8]);
        }
    };
    auto ldA = [&](int buf, int qm) {            // 8 x ds_read_b128
        #pragma unroll
        for (int m4 = 0; m4 < 4; m4++)
            #pragma unroll
            for (int ks = 0; ks < 2; ks++) {
                int ra = (qm * 4 + m4) * 32 + wr * 16 + rr;
                aF[m4][ks] = *(const bf16x8*)
                    &lA[buf][ra * 64 + (((ks * 4 + ko) ^ (rr & 7)) * 8)];
            }
    };
    auto ldB = [&](int buf, int qn) {            // 4 x ds_read_b128
        #pragma unroll
        for (int n2 = 0; n2 < 2; n2++)
            #pragma unroll
            for (int ks = 0; ks < 2; ks++) {
                int rb = (qn * 2 + n2) * 64 + wc * 16 + rr;
                bF[qn][n2][ks] = *(const bf16x8*)
                    &lB[buf][rb * 64 + (((ks * 4 + ko) ^ (rr & 7)) * 8)];
            }
    };
    auto mfmaQ = [&](int qm, int qn) {           // one C-quadrant, 16 MFMA
        __builtin_amdgcn_s_setprio(1);
        #pragma unroll
        for (int m4 = 0; m4 < 4; m4++)
            #pragma unroll
            for (int n2 = 0; n2 < 2; n2++)
                #pragma unroll
                for (int ks = 0; ks < 2; ks++)
                    acc[qm * 4 + m4][qn * 2 + n2] =
                        __builtin_amdgcn_mfma_f32_16x16x32_bf16(
                            aF[m4][ks], bF[qn][n2][ks],
                            acc[qm * 4 + m4][qn * 2 + n2], 0, 0, 0);
        __builtin_amdgcn_s_setprio(0);
    };

    // Prologue: tile0 all 4 halves (order A0,B0,B1,A1 = deadline order) then
    // tile1's A0,B0. vmcnt(4) -> tile0 landed, 2 half-tiles in flight.
    stageA(0, 0, 0); stageB(0, 0, 0); stageB(0, 0, 1); stageA(0, 0, 1);
    stageA(1, 1, 0); stageB(1, 1, 0);
    asm volatile("s_waitcnt vmcnt(4)" ::: "memory");
    __builtin_amdgcn_s_barrier();

    #pragma unroll 1
    for (int i = 0; i < 8; i++) {
        int t1 = 2 * i + 1, t2 = 2 * i + 2, t3 = 2 * i + 3;
        // ---- P1 ----
        ldA(0, 0); ldB(0, 0);
        stageB(1, t1, 1);
        __builtin_amdgcn_s_barrier();
        asm volatile("s_waitcnt lgkmcnt(0)");
        mfmaQ(0, 0);
        __builtin_amdgcn_s_barrier();
        // ---- P2 ----
        ldB(0, 1);
        stageA(1, t1, 1);
        __builtin_amdgcn_s_barrier();
        asm volatile("s_waitcnt lgkmcnt(0)");
        mfmaQ(0, 1);
        __builtin_amdgcn_s_barrier();
        // ---- P3 ----
        ldA(0, 1);
        if (i < 7) stageA(0, t2, 0);
        __builtin_amdgcn_s_barrier();
        asm volatile("s_waitcnt lgkmcnt(0)");
        mfmaQ(1, 0);
        __builtin_amdgcn_s_barrier();
        // ---- P4 ----
        if (i < 7) stageB(0, t2, 0);
        __builtin_amdgcn_s_barrier();
        asm volatile("s_waitcnt lgkmcnt(0)");
        mfmaQ(1, 1);
        if (i < 7) asm volatile("s_waitcnt vmcnt(4)" ::: "memory");
        else       asm volatile("s_waitcnt vmcnt(0)" ::: "memory");
        __builtin_amdgcn_s_barrier();
        // ---- P5 ----
        ldA(1, 0); ldB(1, 0);
        if (i < 7) stageB(0, t2, 1);
        __builtin_amdgcn_s_barrier();
        asm volatile("s_waitcnt lgkmcnt(0)");
        mfmaQ(0, 0);
        __builtin_amdgcn_s_barrier();
        // ---- P6 ----
        ldB(1, 1);
        if (i < 7) stageA(0, t2, 1);
        __builtin_amdgcn_s_barrier();
        asm volatile("s_waitcnt lgkmcnt(0)");
        mfmaQ(0, 1);
        __builtin_amdgcn_s_barrier();
        // ---- P7 ----
        ldA(1, 1);
        if (i < 7) stageA(1, t3, 0);
        __builtin_amdgcn_s_barrier();
        asm volatile("s_waitcnt lgkmcnt(0)");
        mfmaQ(1, 0);
        __builtin_amdgcn_s_barrier();
        // ---- P8 ----
        if (i < 7) stageB(1, t3, 0);
        __builtin_amdgcn_s_barrier();
        asm volatile("s_waitcnt lgkmcnt(0)");
        mfmaQ(1, 1);
        asm volatile("s_waitcnt vmcnt(4)" ::: "memory");
        __builtin_amdgcn_s_barrier();
    }

    // Epilogue: C-write straight from regs (row = A-row with rr->(ko*4+q),
    // col = B-row with rr — same convention the verified 128^2 kernel used).
    #pragma unroll
    for (int mi = 0; mi < 8; mi++)
        #pragma unroll
        for (int ni = 0; ni < 4; ni++)
            #pragma unroll
            for (int q = 0; q < 4; q++) {
                int row = m0 + mi * 32 + wr * 16 + ko * 4 + q;
                int col = n0 + ni * 64 + wc * 16 + rr;
                Out[(size_t)row * DIM + col] = acc[mi][ni][q];
            }
}

extern "C" void kernel_launch(void* const* d_in, const int* in_sizes, int n_in,
                              void* d_out, int out_size, void* d_ws, size_t ws_size,
                              hipStream_t stream) {
    const float* X = (const float*)d_in[0];        // 4*4096*1024 fp32
    const float* W = (const float*)d_in[1];        // 1024*1024 fp32
    float* Out = (float*)d_out;                    // 16384*1024 fp32
    char* ws = (char*)d_ws;
    const size_t MB = 1u << 20;
    unsigned short* Ab  = (unsigned short*)(ws + 0 * MB);
    unsigned short* G   = (unsigned short*)(ws + 2 * MB);
    unsigned short* A2b = (unsigned short*)(ws + 4 * MB);
    unsigned short* Pb  = (unsigned short*)(ws + 6 * MB);
    unsigned short* Rtb = (unsigned short*)(ws + 8 * MB);
    unsigned short* Xb  = (unsigned short*)(ws + 10 * MB);  // 32 MB

    k_init<<<1024, 256, 0, stream>>>(W, Ab, G);
    // g1: A2 = A*A, P = C3*A + C4*A2; + convert X[0 : 8M)
    k_g1<<<256 + 4096, 256, 0, stream>>>(Ab, G, A2b, Pb, X, Xb);
    // g2: T = P*A2; R = I + A + A2/2 + T; emits R^T bf16; + convert X[8M : 16M)
    k_g2<<<256 + 4096, 256, 0, stream>>>(Pb, A2b, Ab, Rtb, X, Xb);
    // big GEMM: 256 blocks (64 m-tiles x 4 n-tiles), 512 threads, 8-phase.
    k_biggemm<<<256, 512, 0, stream>>>(Xb, Rtb, Out);
}

// Round 4
// 165.864 us; speedup vs baseline: 1.0049x; 1.0049x over previous
//
#include <hip/hip_runtime.h>
#include <stdint.h>

#define DIM 1024
#define GLOBAL_AS __attribute__((address_space(1)))
#define LDS_AS __attribute__((address_space(3)))

typedef short bf16x8 __attribute__((ext_vector_type(8)));
typedef float f32x4 __attribute__((ext_vector_type(4)));

// deg-4 Taylor via depth-2: R = I + A + A2/2 + (C3*A + C4*A2)*A2
#define C3f 0.16666667f
#define C4f 0.041666668f

__device__ __forceinline__ unsigned short f32_to_bf16(float f) {
    union { float f; uint32_t u; } v; v.f = f;
    uint32_t u = v.u;
    u += 0x7FFFu + ((u >> 16) & 1u);   // round-to-nearest-even
    return (unsigned short)(u >> 16);
}
__device__ __forceinline__ float bf16_to_f32(unsigned short u) {
    union { uint32_t u; float f; } v; v.u = ((uint32_t)u) << 16;
    return v.f;
}

// async global->LDS, 16B per lane; LDS dst = wave-uniform base + lane*16.
__device__ __forceinline__ void async16(const void* g, void* l) {
    __builtin_amdgcn_global_load_lds((GLOBAL_AS const void*)g,
                                     (LDS_AS void*)l, 16, 0, 0);
}

// Coalesced A = W - W^T via 32x32 LDS tile transpose.
// Ab = bf16(A) (A-operand), G = bf16(-A) = bf16(A^T) (B-operand).
__global__ __launch_bounds__(256) void k_init(const float* __restrict__ W,
        unsigned short* __restrict__ Ab, unsigned short* __restrict__ G) {
    __shared__ float t2[32][33];
    int i0 = (blockIdx.x & 31) * 32, j0 = (blockIdx.x >> 5) * 32;
    int tx = threadIdx.x & 31, ty = threadIdx.x >> 5;
    float t1[4];
    #pragma unroll
    for (int p = 0; p < 4; p++) {
        int r = p * 8 + ty;
        t1[p] = W[(i0 + r) * DIM + j0 + tx];            // coalesced
        t2[r][tx] = W[(j0 + r) * DIM + i0 + tx];        // coalesced
    }
    __syncthreads();
    #pragma unroll
    for (int p = 0; p < 4; p++) {
        int r = p * 8 + ty;
        float a = t1[p] - t2[tx][r];                    // W[i][j] - W[j][i]
        int gi = (i0 + r) * DIM + j0 + tx;
        Ab[gi] = f32_to_bf16(a);
        G[gi]  = f32_to_bf16(-a);
    }
}

// 64x64-tile 1024^3 GEMM body (BK=256, 4 rounds, XOR swizzle, async staging).
// MODE 1 (k_g1): out1 = bf16(acc) = A2; out2 = bf16(C3*A + C4*acc) = P
// MODE 2 (k_g2): v = acc + I + A + A2/2; LDS-transpose; out1 = bf16(v^T) = R^T
// Fused: blocks [0,256) do GEMM; blocks [256, 256+4096) convert X half.
template<int MODE>
__device__ __forceinline__ void gemm_chain_body(
        const unsigned short* __restrict__ P,
        const unsigned short* __restrict__ Qt,
        const unsigned short* __restrict__ Ab,
        const unsigned short* __restrict__ A2b,
        unsigned short* __restrict__ out1,
        unsigned short* __restrict__ out2,
        const float* __restrict__ X,
        unsigned short* __restrict__ Xb,
        size_t xoff) {
    int bid = blockIdx.x;
    int tid = threadIdx.x;
    if (bid >= 256) {                        // ---- convert path (4096 blocks) ----
        size_t id = (size_t)(bid - 256) * 256 + tid;
        const f32x4* p = (const f32x4*)(X + xoff + id * 8);
        f32x4 v0 = p[0], v1 = p[1];
        unsigned short o[8];
        #pragma unroll
        for (int q = 0; q < 4; q++) { o[q] = f32_to_bf16(v0[q]); o[4 + q] = f32_to_bf16(v1[q]); }
        *(bf16x8*)&Xb[xoff + id * 8] = *(bf16x8*)o;
        return;
    }
    __shared__ unsigned short lA[64 * 256];   // 32 KB
    __shared__ unsigned short lB[64 * 256];   // 32 KB
    int m0 = (bid & 15) * 64, n0 = (bid >> 4) * 64;
    int lane = tid & 63, w = tid >> 6;
    int wr = w >> 1, wc = w & 1;
    int rr = lane & 15, ko = lane >> 4;
    f32x4 acc[2][2] = {};
    for (int ks = 0; ks < 4; ks++) {
        int kb = ks * 256;
        #pragma unroll
        for (int i = 0; i < 8; i++) {
            int l = i * 256 + tid;            // 0..2047 = 64 rows x 32 chunks
            int r = l >> 5, cst = l & 31;
            int cd = cst ^ (r & 7);
            async16(&P[(m0 + r) * DIM + kb + cd * 8], &lA[l * 8]);
            async16(&Qt[(n0 + r) * DIM + kb + cd * 8], &lB[l * 8]);
        }
        __syncthreads();
        #pragma unroll
        for (int s = 0; s < 8; s++) {
            int cd = s * 4 + ko;
            bf16x8 af[2], bq[2];
            #pragma unroll
            for (int mi = 0; mi < 2; mi++) {
                int ra = wr * 32 + mi * 16 + rr;
                af[mi] = *(const bf16x8*)&lA[ra * 256 + ((cd ^ (ra & 7)) * 8)];
            }
            #pragma unroll
            for (int ni = 0; ni < 2; ni++) {
                int rb = wc * 32 + ni * 16 + rr;
                bq[ni] = *(const bf16x8*)&lB[rb * 256 + ((cd ^ (rb & 7)) * 8)];
            }
            #pragma unroll
            for (int mi = 0; mi < 2; mi++)
                #pragma unroll
                for (int ni = 0; ni < 2; ni++)
                    acc[mi][ni] = __builtin_amdgcn_mfma_f32_16x16x32_bf16(
                        af[mi], bq[ni], acc[mi][ni], 0, 0, 0);
        }
        __syncthreads();
    }
    if (MODE == 1) {
        #pragma unroll
        for (int mi = 0; mi < 2; mi++)
            #pragma unroll
            for (int ni = 0; ni < 2; ni++)
                #pragma unroll
                for (int q = 0; q < 4; q++) {
                    int rl = wr * 32 + mi * 16 + ko * 4 + q;
                    int cl = wc * 32 + ni * 16 + rr;
                    int gi = (m0 + rl) * DIM + n0 + cl;
                    float v = acc[mi][ni][q];
                    out1[gi] = f32_to_bf16(v);
                    float a = bf16_to_f32(Ab[gi]);
                    out2[gi] = f32_to_bf16(C3f * a + C4f * v);
                }
    } else {
        float* tb = (float*)lA;               // 64*65*4 = 16.6 KB
        #pragma unroll
        for (int mi = 0; mi < 2; mi++)
            #pragma unroll
            for (int ni = 0; ni < 2; ni++)
                #pragma unroll
                for (int q = 0; q < 4; q++) {
                    int rl = wr * 32 + mi * 16 + ko * 4 + q;
                    int cl = wc * 32 + ni * 16 + rr;
                    int gi = (m0 + rl) * DIM + n0 + cl;
                    float a = bf16_to_f32(Ab[gi]);
                    float a2 = bf16_to_f32(A2b[gi]);
                    float d = (m0 + rl == n0 + cl) ? 1.0f : 0.0f;
                    tb[cl * 65 + rl] = acc[mi][ni][q] + d + a + 0.5f * a2;
                }
        __syncthreads();
        #pragma unroll
        for (int q = 0; q < 16; q++) {
            int l = tid * 16 + q;
            int orow = l >> 6, ocol = l & 63;
            out1[(n0 + orow) * DIM + m0 + ocol] = f32_to_bf16(tb[orow * 65 + ocol]);
        }
    }
}

__global__ __launch_bounds__(256) void k_g1(
        const unsigned short* __restrict__ Ab, const unsigned short* __restrict__ G,
        unsigned short* __restrict__ A2b, unsigned short* __restrict__ Pb,
        const float* __restrict__ X, unsigned short* __restrict__ Xb) {
    gemm_chain_body<1>(Ab, G, Ab, nullptr, A2b, Pb, X, Xb, 0);
}

__global__ __launch_bounds__(256) void k_g2(
        const unsigned short* __restrict__ Pb, const unsigned short* __restrict__ A2b,
        const unsigned short* __restrict__ Ab, unsigned short* __restrict__ Rtb,
        const float* __restrict__ X, unsigned short* __restrict__ Xb) {
    // A2^T = A2 (symmetric), so Qt = A2b row-major directly.
    gemm_chain_body<2>(Pb, A2b, Ab, A2b, Rtb, nullptr, X, Xb, (size_t)8388608);
}

// Out(16384x1024) = Xb(bf16) @ R, with Rtb = R^T row-major bf16.
// 256x256 tile, BK=64, 512 threads (8 waves, 2M x 4N), 128 KiB LDS dbuf,
// 8-phase schedule. R3 changes vs R2 (post-mortem driven):
//  (1) depth-3 prefetch: every stage issued at the earliest WAR-legal phase,
//      vmcnt(6) at P4/P8 (m201's exact spec; R2 was depth-2/vmcnt(4), leaving
//      late stages only ~2 phases of latency cover -> 1.56x slower iters).
//  (2) peeled final iteration with per-quadrant epilogue: quadrant (qm,qn)'s
//      accumulation finishes at P5/P6/P7/P8 of the last iteration; its stores
//      issue right there, overlapping ~3/4 of the 68 MB write tail with MFMA.
//
// Steady-state stage slots (iter i: t0=2i in b0 @P1-P4, t1=2i+1 in b1 @P5-P8):
//   P1: b1.A1<-t1   P2: b0.A0<-t2   P3: b0.B0<-t2   P4: b0.B1<-t2
//   P5: b0.A1<-t2   P6: b1.A0<-t3   P7: b1.B0<-t3   P8: b1.B1<-t3
// Last-reads: b0: A0@P1,B0@P1,B1@P2,A1@P3; b1: A0@P5,B0@P5,B1@P6,A1@P7 ->
// every stage lands >=1 barrier after its region's last ds_read (WAR safe).
// vmcnt(6)@P4: worst queue [P6-,P7-,P8-,P1,P2,P3,P4] -> oldest 8 loads done =
// all of b1(t1). vmcnt(6)@P8: queue [P2..P8] -> P2..P5 done = all of b0(t2).
__global__ __launch_bounds__(512, 2) void k_biggemm(
        const unsigned short* __restrict__ Xb,
        const unsigned short* __restrict__ Rtb,
        float* __restrict__ Out) {
    __shared__ unsigned short lA[2][256 * 64];   // 64 KB
    __shared__ unsigned short lB[2][256 * 64];   // 64 KB
    int tid = threadIdx.x;
    int bid = blockIdx.x;
    // XCD swizzle (nwg=256, 256%8==0 -> bijective): XCD x gets 8 m-panels with
    // all 4 n-tiles -> the 4 blocks sharing an Xb m-panel sit on one XCD's L2.
    int s = (bid & 7) * 32 + (bid >> 3);
    int m0 = (s >> 2) * 256, n0 = (s & 3) * 256;
    int lane = tid & 63, w = tid >> 6;
    int wr = w >> 2, wc = w & 3;                 // 2 x 4 wave grid
    int rr = lane & 15, ko = (lane >> 4) & 3;

    f32x4 acc[8][4] = {};                        // 128 x 64 per wave
    bf16x8 aF[4][2], bF[2][2][2];

    // Stage one half (128 rows) of the A/B K-tile kt into buf: 2 loads/thread.
    // LDS dest linear; source chunk pre-swizzled (c ^ (r&7)) so swizzled
    // ds_read finds data in place (involution).
    auto stageA = [&](int buf, int kt, int h) {
        #pragma unroll
        for (int l = 0; l < 2; l++) {
            int L = h * 1024 + l * 512 + tid;
            int r = L >> 3, c = L & 7;
            async16(&Xb[(size_t)(m0 + r) * DIM + kt * 64 + ((c ^ (r & 7)) * 8)],
                    &lA[buf][L * 8]);
        }
    };
    auto stageB = [&](int buf, int kt, int h) {
        #pragma unroll
        for (int l = 0; l < 2; l++) {
            int L = h * 1024 + l * 512 + tid;
            int r = L >> 3, c = L & 7;
            async16(&Rtb[(size_t)(n0 + r) * DIM + kt * 64 + ((c ^ (r & 7)) * 8)],
                    &lB[buf][L * 8]);
        }
    };
    auto ldA = [&](int buf, int qm) {            // 8 x ds_read_b128
        #pragma unroll
        for (int m4 = 0; m4 < 4; m4++)
            #pragma unroll
            for (int ks = 0; ks < 2; ks++) {
                int ra = (qm * 4 + m4) * 32 + wr * 16 + rr;
                aF[m4][ks] = *(const bf16x8*)
                    &lA[buf][ra * 64 + (((ks * 4 + ko) ^ (rr & 7)) * 8)];
            }
    };
    auto ldB = [&](int buf, int qn) {            // 4 x ds_read_b128
        #pragma unroll
        for (int n2 = 0; n2 < 2; n2++)
            #pragma unroll
            for (int ks = 0; ks < 2; ks++) {
                int rb = (qn * 2 + n2) * 64 + wc * 16 + rr;
                bF[qn][n2][ks] = *(const bf16x8*)
                    &lB[buf][rb * 64 + (((ks * 4 + ko) ^ (rr & 7)) * 8)];
            }
    };
    auto mfmaQ = [&](int qm, int qn) {           // one C-quadrant, 16 MFMA
        __builtin_amdgcn_s_setprio(1);
        #pragma unroll
        for (int m4 = 0; m4 < 4; m4++)
            #pragma unroll
            for (int n2 = 0; n2 < 2; n2++)
                #pragma unroll
                for (int ks = 0; ks < 2; ks++)
                    acc[qm * 4 + m4][qn * 2 + n2] =
                        __builtin_amdgcn_mfma_f32_16x16x32_bf16(
                            aF[m4][ks], bF[qn][n2][ks],
                            acc[qm * 4 + m4][qn * 2 + n2], 0, 0, 0);
        __builtin_amdgcn_s_setprio(0);
    };
    auto epiQ = [&](int qm, int qn) {            // store one finished quadrant
        #pragma unroll
        for (int m4 = 0; m4 < 4; m4++)
            #pragma unroll
            for (int n2 = 0; n2 < 2; n2++)
                #pragma unroll
                for (int q = 0; q < 4; q++) {
                    int row = m0 + (qm * 4 + m4) * 32 + wr * 16 + ko * 4 + q;
                    int col = n0 + (qn * 2 + n2) * 64 + wc * 16 + rr;
                    Out[(size_t)row * DIM + col] = acc[qm * 4 + m4][qn * 2 + n2][q];
                }
    };

    // Prologue: all of t0 (deadline order) + 3 halves of t1; vmcnt(6) lands
    // exactly t0's 8 loads. In-loop P1 supplies t1's 4th half (A1).
    stageA(0, 0, 0); stageB(0, 0, 0); stageB(0, 0, 1); stageA(0, 0, 1);
    stageA(1, 1, 0); stageB(1, 1, 0); stageB(1, 1, 1);
    asm volatile("s_waitcnt vmcnt(6)" ::: "memory");
    __builtin_amdgcn_s_barrier();

    #pragma unroll 1
    for (int i = 0; i < 7; i++) {                // t3 max = 15: no guards needed
        int t1 = 2 * i + 1, t2 = 2 * i + 2, t3 = 2 * i + 3;
        // ---- P1 ----
        ldA(0, 0); ldB(0, 0);
        stageA(1, t1, 1);
        __builtin_amdgcn_s_barrier();
        asm volatile("s_waitcnt lgkmcnt(0)");
        mfmaQ(0, 0);
        __builtin_amdgcn_s_barrier();
        // ---- P2 ----
        ldB(0, 1);
        stageA(0, t2, 0);
        __builtin_amdgcn_s_barrier();
        asm volatile("s_waitcnt lgkmcnt(0)");
        mfmaQ(0, 1);
        __builtin_amdgcn_s_barrier();
        // ---- P3 ----
        ldA(0, 1);
        stageB(0, t2, 0);
        __builtin_amdgcn_s_barrier();
        asm volatile("s_waitcnt lgkmcnt(0)");
        mfmaQ(1, 0);
        __builtin_amdgcn_s_barrier();
        // ---- P4 ----
        stageB(0, t2, 1);
        __builtin_amdgcn_s_barrier();
        asm volatile("s_waitcnt lgkmcnt(0)");
        mfmaQ(1, 1);
        asm volatile("s_waitcnt vmcnt(6)" ::: "memory");
        __builtin_amdgcn_s_barrier();
        // ---- P5 ----
        ldA(1, 0); ldB(1, 0);
        stageA(0, t2, 1);
        __builtin_amdgcn_s_barrier();
        asm volatile("s_waitcnt lgkmcnt(0)");
        mfmaQ(0, 0);
        __builtin_amdgcn_s_barrier();
        // ---- P6 ----
        ldB(1, 1);
        stageA(1, t3, 0);
        __builtin_amdgcn_s_barrier();
        asm volatile("s_waitcnt lgkmcnt(0)");
        mfmaQ(0, 1);
        __builtin_amdgcn_s_barrier();
        // ---- P7 ----
        ldA(1, 1);
        stageB(1, t3, 0);
        __builtin_amdgcn_s_barrier();
        asm volatile("s_waitcnt lgkmcnt(0)");
        mfmaQ(1, 0);
        __builtin_amdgcn_s_barrier();
        // ---- P8 ----
        stageB(1, t3, 1);
        __builtin_amdgcn_s_barrier();
        asm volatile("s_waitcnt lgkmcnt(0)");
        mfmaQ(1, 1);
        asm volatile("s_waitcnt vmcnt(6)" ::: "memory");
        __builtin_amdgcn_s_barrier();
    }

    // Peeled final iteration (t0=14 in b0, t1=15 in b1): no t2/t3 stages;
    // per-quadrant stores interleave with the last 4 MFMA phases.
    // ---- P1 ----
    ldA(0, 0); ldB(0, 0);
    stageA(1, 15, 1);
    __builtin_amdgcn_s_barrier();
    asm volatile("s_waitcnt lgkmcnt(0)");
    mfmaQ(0, 0);
    __builtin_amdgcn_s_barrier();
    // ---- P2 ----
    ldB(0, 1);
    __builtin_amdgcn_s_barrier();
    asm volatile("s_waitcnt lgkmcnt(0)");
    mfmaQ(0, 1);
    __builtin_amdgcn_s_barrier();
    // ---- P3 ----
    ldA(0, 1);
    __builtin_amdgcn_s_barrier();
    asm volatile("s_waitcnt lgkmcnt(0)");
    mfmaQ(1, 0);
    __builtin_amdgcn_s_barrier();
    // ---- P4 ----
    __builtin_amdgcn_s_barrier();
    asm volatile("s_waitcnt lgkmcnt(0)");
    mfmaQ(1, 1);
    asm volatile("s_waitcnt vmcnt(0)" ::: "memory");
    __builtin_amdgcn_s_barrier();
    // ---- P5 ----
    ldA(1, 0); ldB(1, 0);
    __builtin_amdgcn_s_barrier();
    asm volatile("s_waitcnt lgkmcnt(0)");
    mfmaQ(0, 0);
    epiQ(0, 0);
    __builtin_amdgcn_s_barrier();
    // ---- P6 ----
    ldB(1, 1);
    __builtin_amdgcn_s_barrier();
    asm volatile("s_waitcnt lgkmcnt(0)");
    mfmaQ(0, 1);
    epiQ(0, 1);
    __builtin_amdgcn_s_barrier();
    // ---- P7 ----
    ldA(1, 1);
    __builtin_amdgcn_s_barrier();
    asm volatile("s_waitcnt lgkmcnt(0)");
    mfmaQ(1, 0);
    epiQ(1, 0);
    __builtin_amdgcn_s_barrier();
    // ---- P8 ----
    asm volatile("s_waitcnt lgkmcnt(0)");
    mfmaQ(1, 1);
    epiQ(1, 1);
}

extern "C" void kernel_launch(void* const* d_in, const int* in_sizes, int n_in,
                              void* d_out, int out_size, void* d_ws, size_t ws_size,
                              hipStream_t stream) {
    const float* X = (const float*)d_in[0];        // 4*4096*1024 fp32
    const float* W = (const float*)d_in[1];        // 1024*1024 fp32
    float* Out = (float*)d_out;                    // 16384*1024 fp32
    char* ws = (char*)d_ws;
    const size_t MB = 1u << 20;
    unsigned short* Ab  = (unsigned short*)(ws + 0 * MB);
    unsigned short* G   = (unsigned short*)(ws + 2 * MB);
    unsigned short* A2b = (unsigned short*)(ws + 4 * MB);
    unsigned short* Pb  = (unsigned short*)(ws + 6 * MB);
    unsigned short* Rtb = (unsigned short*)(ws + 8 * MB);
    unsigned short* Xb  = (unsigned short*)(ws + 10 * MB);  // 32 MB

    k_init<<<1024, 256, 0, stream>>>(W, Ab, G);
    // g1: A2 = A*A, P = C3*A + C4*A2; + convert X[0 : 8M)
    k_g1<<<256 + 4096, 256, 0, stream>>>(Ab, G, A2b, Pb, X, Xb);
    // g2: T = P*A2; R = I + A + A2/2 + T; emits R^T bf16; + convert X[8M : 16M)
    k_g2<<<256 + 4096, 256, 0, stream>>>(Pb, A2b, Ab, Rtb, X, Xb);
    // big GEMM: 256 blocks (64 m-tiles x 4 n-tiles), 512 threads, 8-phase.
    k_biggemm<<<256, 512, 0, stream>>>(Xb, Rtb, Out);
}

// Round 5
// 164.764 us; speedup vs baseline: 1.0116x; 1.0067x over previous
//
#include <hip/hip_runtime.h>
#include <stdint.h>

#define DIM 1024
#define GLOBAL_AS __attribute__((address_space(1)))
#define LDS_AS __attribute__((address_space(3)))

typedef short bf16x8 __attribute__((ext_vector_type(8)));
typedef float f32x4 __attribute__((ext_vector_type(4)));

// deg-4 Taylor via depth-2: R = I + A + A2/2 + (C3*A + C4*A2)*A2
#define C3f 0.16666667f
#define C4f 0.041666668f

__device__ __forceinline__ unsigned short f32_to_bf16(float f) {
    union { float f; uint32_t u; } v; v.f = f;
    uint32_t u = v.u;
    u += 0x7FFFu + ((u >> 16) & 1u);   // round-to-nearest-even
    return (unsigned short)(u >> 16);
}
__device__ __forceinline__ float bf16_to_f32(unsigned short u) {
    union { uint32_t u; float f; } v; v.u = ((uint32_t)u) << 16;
    return v.f;
}

// async global->LDS, 16B per lane; LDS dst = wave-uniform base + lane*16.
__device__ __forceinline__ void async16(const void* g, void* l) {
    __builtin_amdgcn_global_load_lds((GLOBAL_AS const void*)g,
                                     (LDS_AS void*)l, 16, 0, 0);
}

// Fused: blocks [0,1024) compute A = W - W^T (bf16 Ab, G = -A); blocks
// [1024, 1024+8192) convert ALL of X fp32 -> Xb bf16.
// Rationale (R4): X->Xb has no dependency on the R-chain (Xb is consumed
// only by k_biggemm, two launches later). Fusing converts into g1/g2 made
// their staged-GEMM vmcnt(0) drains queue behind ~48 MB of convert traffic.
__global__ __launch_bounds__(256) void k_initconv(const float* __restrict__ W,
        unsigned short* __restrict__ Ab, unsigned short* __restrict__ G,
        const float* __restrict__ X, unsigned short* __restrict__ Xb) {
    __shared__ float t2[32][33];
    int bid = blockIdx.x;
    int tid = threadIdx.x;
    if (bid >= 1024) {                       // ---- convert path (8192 blocks) ----
        size_t id = (size_t)(bid - 1024) * 256 + tid;
        const f32x4* p = (const f32x4*)(X + id * 8);
        f32x4 v0 = p[0], v1 = p[1];
        unsigned short o[8];
        #pragma unroll
        for (int q = 0; q < 4; q++) { o[q] = f32_to_bf16(v0[q]); o[4 + q] = f32_to_bf16(v1[q]); }
        *(bf16x8*)&Xb[id * 8] = *(bf16x8*)o;
        return;
    }
    // ---- init path: coalesced A = W - W^T via 32x32 LDS tile transpose ----
    int i0 = (bid & 31) * 32, j0 = (bid >> 5) * 32;
    int tx = tid & 31, ty = tid >> 5;
    float t1[4];
    #pragma unroll
    for (int p = 0; p < 4; p++) {
        int r = p * 8 + ty;
        t1[p] = W[(i0 + r) * DIM + j0 + tx];            // coalesced
        t2[r][tx] = W[(j0 + r) * DIM + i0 + tx];        // coalesced
    }
    __syncthreads();
    #pragma unroll
    for (int p = 0; p < 4; p++) {
        int r = p * 8 + ty;
        float a = t1[p] - t2[tx][r];                    // W[i][j] - W[j][i]
        int gi = (i0 + r) * DIM + j0 + tx;
        Ab[gi] = f32_to_bf16(a);
        G[gi]  = f32_to_bf16(-a);
    }
}

// 64x64-tile 1024^3 GEMM body (BK=256, 4 rounds, XOR swizzle, async staging).
// MODE 1 (k_g1): out1 = bf16(acc) = A2; out2 = bf16(C3*A + C4*acc) = P
// MODE 2 (k_g2): v = acc + I + A + A2/2; LDS-transpose; out1 = bf16(v^T) = R^T
// Pure GEMM now (converts moved to k_initconv): grid is exactly 256 blocks.
template<int MODE>
__device__ __forceinline__ void gemm_chain_body(
        const unsigned short* __restrict__ P,
        const unsigned short* __restrict__ Qt,
        const unsigned short* __restrict__ Ab,
        const unsigned short* __restrict__ A2b,
        unsigned short* __restrict__ out1,
        unsigned short* __restrict__ out2) {
    int bid = blockIdx.x;
    int tid = threadIdx.x;
    __shared__ unsigned short lA[64 * 256];   // 32 KB
    __shared__ unsigned short lB[64 * 256];   // 32 KB
    int m0 = (bid & 15) * 64, n0 = (bid >> 4) * 64;
    int lane = tid & 63, w = tid >> 6;
    int wr = w >> 1, wc = w & 1;
    int rr = lane & 15, ko = lane >> 4;
    f32x4 acc[2][2] = {};
    for (int ks = 0; ks < 4; ks++) {
        int kb = ks * 256;
        #pragma unroll
        for (int i = 0; i < 8; i++) {
            int l = i * 256 + tid;            // 0..2047 = 64 rows x 32 chunks
            int r = l >> 5, cst = l & 31;
            int cd = cst ^ (r & 7);
            async16(&P[(m0 + r) * DIM + kb + cd * 8], &lA[l * 8]);
            async16(&Qt[(n0 + r) * DIM + kb + cd * 8], &lB[l * 8]);
        }
        __syncthreads();
        #pragma unroll
        for (int s = 0; s < 8; s++) {
            int cd = s * 4 + ko;
            bf16x8 af[2], bq[2];
            #pragma unroll
            for (int mi = 0; mi < 2; mi++) {
                int ra = wr * 32 + mi * 16 + rr;
                af[mi] = *(const bf16x8*)&lA[ra * 256 + ((cd ^ (ra & 7)) * 8)];
            }
            #pragma unroll
            for (int ni = 0; ni < 2; ni++) {
                int rb = wc * 32 + ni * 16 + rr;
                bq[ni] = *(const bf16x8*)&lB[rb * 256 + ((cd ^ (rb & 7)) * 8)];
            }
            #pragma unroll
            for (int mi = 0; mi < 2; mi++)
                #pragma unroll
                for (int ni = 0; ni < 2; ni++)
                    acc[mi][ni] = __builtin_amdgcn_mfma_f32_16x16x32_bf16(
                        af[mi], bq[ni], acc[mi][ni], 0, 0, 0);
        }
        __syncthreads();
    }
    if (MODE == 1) {
        #pragma unroll
        for (int mi = 0; mi < 2; mi++)
            #pragma unroll
            for (int ni = 0; ni < 2; ni++)
                #pragma unroll
                for (int q = 0; q < 4; q++) {
                    int rl = wr * 32 + mi * 16 + ko * 4 + q;
                    int cl = wc * 32 + ni * 16 + rr;
                    int gi = (m0 + rl) * DIM + n0 + cl;
                    float v = acc[mi][ni][q];
                    out1[gi] = f32_to_bf16(v);
                    float a = bf16_to_f32(Ab[gi]);
                    out2[gi] = f32_to_bf16(C3f * a + C4f * v);
                }
    } else {
        float* tb = (float*)lA;               // 64*65*4 = 16.6 KB
        #pragma unroll
        for (int mi = 0; mi < 2; mi++)
            #pragma unroll
            for (int ni = 0; ni < 2; ni++)
                #pragma unroll
                for (int q = 0; q < 4; q++) {
                    int rl = wr * 32 + mi * 16 + ko * 4 + q;
                    int cl = wc * 32 + ni * 16 + rr;
                    int gi = (m0 + rl) * DIM + n0 + cl;
                    float a = bf16_to_f32(Ab[gi]);
                    float a2 = bf16_to_f32(A2b[gi]);
                    float d = (m0 + rl == n0 + cl) ? 1.0f : 0.0f;
                    tb[cl * 65 + rl] = acc[mi][ni][q] + d + a + 0.5f * a2;
                }
        __syncthreads();
        #pragma unroll
        for (int q = 0; q < 16; q++) {
            int l = tid * 16 + q;
            int orow = l >> 6, ocol = l & 63;
            out1[(n0 + orow) * DIM + m0 + ocol] = f32_to_bf16(tb[orow * 65 + ocol]);
        }
    }
}

__global__ __launch_bounds__(256) void k_g1(
        const unsigned short* __restrict__ Ab, const unsigned short* __restrict__ G,
        unsigned short* __restrict__ A2b, unsigned short* __restrict__ Pb) {
    gemm_chain_body<1>(Ab, G, Ab, nullptr, A2b, Pb);
}

__global__ __launch_bounds__(256) void k_g2(
        const unsigned short* __restrict__ Pb, const unsigned short* __restrict__ A2b,
        const unsigned short* __restrict__ Ab, unsigned short* __restrict__ Rtb) {
    // A2^T = A2 (symmetric), so Qt = A2b row-major directly.
    gemm_chain_body<2>(Pb, A2b, Ab, A2b, Rtb, nullptr);
}

// Out(16384x1024) = Xb(bf16) @ R, R^T row-major bf16 (Rtb).
// R0-measured winner (44.8 us, MfmaUtil 30%): 128x128 tiles, BK=64, 32 KB LDS,
// grid 1024 = 4 blocks/CU; bid%8 == m%8 keeps an m-strip's n-tiles on one XCD.
__global__ __launch_bounds__(256, 4) void k_biggemm(
        const unsigned short* __restrict__ Xb,
        const unsigned short* __restrict__ Rtb,
        float* __restrict__ Out) {
    __shared__ unsigned short lX[128 * 64];   // 16 KB
    __shared__ unsigned short lB[128 * 64];   // 16 KB
    int tid = threadIdx.x;
    int bid = blockIdx.x;
    int m0 = (bid & 127) * 128, n0 = (bid >> 7) * 128;
    int lane = tid & 63, w = tid >> 6;
    int wr = w >> 1, wc = w & 1;
    int rr = lane & 15, ko = lane >> 4;
    f32x4 acc[4][4] = {};
    for (int kb = 0; kb < DIM; kb += 64) {
        #pragma unroll
        for (int i = 0; i < 4; i++) {         // 128 rows x 8 chunks each array
            int l = i * 256 + tid;
            int r = l >> 3, cst = l & 7;
            int cd = cst ^ (r & 7);
            async16(&Xb[(size_t)(m0 + r) * DIM + kb + cd * 8], &lX[l * 8]);
            async16(&Rtb[(n0 + r) * DIM + kb + cd * 8], &lB[l * 8]);
        }
        __syncthreads();
        #pragma unroll
        for (int s = 0; s < 2; s++) {
            int cd = s * 4 + ko;
            bf16x8 af[4], bq[4];
            #pragma unroll
            for (int mi = 0; mi < 4; mi++) {
                int ra = wr * 64 + mi * 16 + rr;
                af[mi] = *(const bf16x8*)&lX[ra * 64 + ((cd ^ (ra & 7)) * 8)];
            }
            #pragma unroll
            for (int ni = 0; ni < 4; ni++) {
                int rb = wc * 64 + ni * 16 + rr;
                bq[ni] = *(const bf16x8*)&lB[rb * 64 + ((cd ^ (rb & 7)) * 8)];
            }
            #pragma unroll
            for (int mi = 0; mi < 4; mi++)
                #pragma unroll
                for (int ni = 0; ni < 4; ni++)
                    acc[mi][ni] = __builtin_amdgcn_mfma_f32_16x16x32_bf16(
                        af[mi], bq[ni], acc[mi][ni], 0, 0, 0);
        }
        __syncthreads();
    }
    #pragma unroll
    for (int mi = 0; mi < 4; mi++)
        #pragma unroll
        for (int ni = 0; ni < 4; ni++)
            #pragma unroll
            for (int q = 0; q < 4; q++) {
                int row = m0 + wr * 64 + mi * 16 + ko * 4 + q;
                int col = n0 + wc * 64 + ni * 16 + rr;
                Out[(size_t)row * DIM + col] = acc[mi][ni][q];
            }
}

extern "C" void kernel_launch(void* const* d_in, const int* in_sizes, int n_in,
                              void* d_out, int out_size, void* d_ws, size_t ws_size,
                              hipStream_t stream) {
    const float* X = (const float*)d_in[0];        // 4*4096*1024 fp32
    const float* W = (const float*)d_in[1];        // 1024*1024 fp32
    float* Out = (float*)d_out;                    // 16384*1024 fp32
    char* ws = (char*)d_ws;
    const size_t MB = 1u << 20;
    unsigned short* Ab  = (unsigned short*)(ws + 0 * MB);
    unsigned short* G   = (unsigned short*)(ws + 2 * MB);
    unsigned short* A2b = (unsigned short*)(ws + 4 * MB);
    unsigned short* Pb  = (unsigned short*)(ws + 6 * MB);
    unsigned short* Rtb = (unsigned short*)(ws + 8 * MB);
    unsigned short* Xb  = (unsigned short*)(ws + 10 * MB);  // 32 MB

    // init A + convert ALL of X (independent of the R-chain; Xb used only by
    // k_biggemm, two launches later).
    k_initconv<<<1024 + 8192, 256, 0, stream>>>(W, Ab, G, X, Xb);
    // g1: A2 = A*A, P = C3*A + C4*A2   (pure GEMM, 256 blocks)
    k_g1<<<256, 256, 0, stream>>>(Ab, G, A2b, Pb);
    // g2: T = P*A2; R = I + A + A2/2 + T; emits R^T bf16
    k_g2<<<256, 256, 0, stream>>>(Pb, A2b, Ab, Rtb);
    // big GEMM: 1024 blocks (128 m x 8 n), 128x128 tiles, 4 blocks/CU.
    k_biggemm<<<1024, 256, 0, stream>>>(Xb, Rtb, Out);
}